// Round 1
// baseline (379.244 us; speedup 1.0000x reference)
//
#include <hip/hip_runtime.h>
#include <math.h>

#define N   8192
#define NZ  256
#define NC  128
#define DT  0.1f

typedef float fx4 __attribute__((ext_vector_type(4)));

__device__ __forceinline__ float wave_reduce(float v) {
    #pragma unroll
    for (int off = 32; off > 0; off >>= 1)
        v += __shfl_down(v, off, 64);
    return v;
}

__device__ __forceinline__ float dot4v(fx4 a, fx4 b) {
    return a.x * b.x + a.y * b.y + a.z * b.z + a.w * b.w;
}

// nontemporal 16B load: W streams that are single-use bypass-hint so the hot
// r/z/x/b vectors (and the reused W_rz) stay cache-resident.
__device__ __forceinline__ fx4 ntload4(const float* p) {
    return __builtin_nontemporal_load((const fx4*)p);
}
__device__ __forceinline__ fx4 ld4(const float* p) {
    return *(const fx4*)p;
}

// K1: r = tanh(x + b), float4-vectorized. 64-thread blocks -> 32 blocks to
// spread the tanh latency across more CUs than the old 8-block launch.
__global__ __launch_bounds__(64) void k1_r(const float* __restrict__ x,
                                           const float* __restrict__ b,
                                           float* __restrict__ r) {
    int i = blockIdx.x * blockDim.x + threadIdx.x;
    fx4 xv = ld4(x + 4 * i), bv = ld4(b + 4 * i), rv;
    rv.x = tanhf(xv.x + bv.x);
    rv.y = tanhf(xv.y + bv.y);
    rv.z = tanhf(xv.z + bv.z);
    rv.w = tanhf(xv.w + bv.w);
    *(fx4*)(r + 4 * i) = rv;
}

// K3a: fused {z = W_rz @ r} + {acc_row = W_rr[row].r + W_epsr[row].eps
//       + W_cr[row].c}. The 64 leading blocks compute z (wave-per-row);
// the remaining 2048 blocks stream W_rr. No ordering between the two groups
// is required inside this kernel: z and accv are both consumed only by K3b,
// which launches after a full dependency barrier. This removes the old K2
// from the serial critical path — its 8.4 MB hides under the 268 MB W_rr
// stream.
__global__ __launch_bounds__(256) void k3a(const float* __restrict__ Wrr,
                                           const float* __restrict__ Wepsr,
                                           const float* __restrict__ Wcr,
                                           const float* __restrict__ Wrz,
                                           const float* __restrict__ r,
                                           const float* __restrict__ eps,
                                           const float* __restrict__ c,
                                           float* __restrict__ z,
                                           float* __restrict__ accv) {
    int wave = threadIdx.x >> 6, lane = threadIdx.x & 63;

    if (blockIdx.x < NZ / 4) {
        // z rows: wave-per-row over W_rz (regular loads: W_rz is re-read by
        // K4, keep it L2/L3-resident).
        int row = blockIdx.x * 4 + wave;
        const float* wr = Wrz + (size_t)row * N;
        float acc = 0.f;
        #pragma unroll 8
        for (int k = 0; k < (N / 4) / 64; ++k) {   // 32 iters
            int idx = 4 * (lane + k * 64);
            acc += dot4v(ld4(wr + idx), ld4(r + idx));
        }
        acc = wave_reduce(acc);
        if (lane == 0) z[row] = acc;
    } else {
        // main rows: one wave per row, unroll 16 -> 16 KB of W in flight
        // per wave for deep HBM pipelining.
        int row = (blockIdx.x - NZ / 4) * 4 + wave;
        const float* wr = Wrr + (size_t)row * N;
        float acc = 0.f;
        #pragma unroll 16
        for (int k = 0; k < (N / 4) / 64; ++k) {   // 32 iters
            int idx = 4 * (lane + k * 64);
            acc += dot4v(ntload4(wr + idx), ld4(r + idx));
        }
        {   // W_epsr[row] (256) . eps
            acc += dot4v(ntload4(Wepsr + (size_t)row * NZ + 4 * lane),
                         ld4(eps + 4 * lane));
        }
        if (lane < NC / 4) {   // W_cr[row] (128) . c
            acc += dot4v(ntload4(Wcr + (size_t)row * NC + 4 * lane),
                         ld4(c + 4 * lane));
        }
        acc = wave_reduce(acc);
        if (lane == 0) accv[row] = acc;
    }
}

// K3b: add the z-dependent term + Euler/tanh epilogue. 8.4 MB of W_zr only.
__global__ __launch_bounds__(256) void k3b(const float* __restrict__ Wzr,
                                           const float* __restrict__ z,
                                           const float* __restrict__ accv,
                                           const float* __restrict__ x,
                                           const float* __restrict__ b,
                                           float* __restrict__ out) {
    int row  = (blockIdx.x * blockDim.x + threadIdx.x) >> 6;
    int lane = threadIdx.x & 63;
    float t = dot4v(ntload4(Wzr + (size_t)row * NZ + 4 * lane),
                    ld4(z + 4 * lane));
    t = wave_reduce(t);
    if (lane == 0) {
        float xi = x[row];
        float dx = accv[row] + t - xi;
        float xn = xi + DT * dx;
        float rn = tanhf(xn + b[row]);
        out[row]     = xn;   // x_new
        out[N + row] = rn;   // r_new
    }
}

// Block-per-row matvec for the head readouts. Regular (cacheable) loads:
// W_rz should hit L3 from K3a's pass; W_rc is only 4.2 MB.
__device__ __forceinline__ float block_row_dot(const float* __restrict__ row,
                                               const float* __restrict__ v) {
    int t = threadIdx.x;
    float acc = 0.f;
    #pragma unroll
    for (int j = 0; j < (N / 4) / 256; ++j) {   // 8 iters
        int idx = 4 * (t + j * 256);
        acc += dot4v(ld4(row + idx), ld4(v + idx));
    }
    acc = wave_reduce(acc);
    __shared__ float part[4];
    int wave = t >> 6, lane = t & 63;
    if (lane == 0) part[wave] = acc;
    __syncthreads();
    return part[0] + part[1] + part[2] + part[3];
}

// K4: z_new = W_rz @ r_new ; c_new = W_rc @ r_new ; eps_new = z_new - z_tilde
__global__ __launch_bounds__(256) void k4_heads(const float* __restrict__ Wrz,
                                                const float* __restrict__ Wrc,
                                                const float* __restrict__ rnew,
                                                const float* __restrict__ ztilde,
                                                float* __restrict__ out) {
    int row = blockIdx.x;
    const float* Wrow = (row < NZ) ? (Wrz + (size_t)row * N)
                                   : (Wrc + (size_t)(row - NZ) * N);
    float d = block_row_dot(Wrow, rnew);
    if (threadIdx.x == 0) {
        if (row < NZ) {
            out[2 * N + row]           = d;                 // z_new
            out[2 * N + NZ + NC + row] = d - ztilde[row];   // eps_new
        } else {
            out[2 * N + NZ + (row - NZ)] = d;               // c_new
        }
    }
}

extern "C" void kernel_launch(void* const* d_in, const int* in_sizes, int n_in,
                              void* d_out, int out_size, void* d_ws, size_t ws_size,
                              hipStream_t stream) {
    const float* x      = (const float*)d_in[0];
    const float* eps    = (const float*)d_in[1];
    const float* c      = (const float*)d_in[2];
    const float* ztilde = (const float*)d_in[3];
    const float* Wrr    = (const float*)d_in[4];
    const float* Wzr    = (const float*)d_in[5];
    const float* Wcr    = (const float*)d_in[6];
    const float* Wepsr  = (const float*)d_in[7];
    const float* Wrz    = (const float*)d_in[8];
    const float* Wrc    = (const float*)d_in[9];
    const float* b      = (const float*)d_in[10];
    float* out = (float*)d_out;

    float* r    = (float*)d_ws;     // N floats
    float* z    = r + N;            // NZ floats (16B-aligned: N%4==0)
    float* accv = z + NZ;           // N floats

    k1_r<<<N / (64 * 4), 64, 0, stream>>>(x, b, r);
    k3a<<<NZ / 4 + N / 4, 256, 0, stream>>>(Wrr, Wepsr, Wcr, Wrz,
                                            r, eps, c, z, accv);
    k3b<<<N / 4, 256, 0, stream>>>(Wzr, z, accv, x, b, out);
    k4_heads<<<NZ + NC, 256, 0, stream>>>(Wrz, Wrc, out + N, ztilde, out);
}